// Round 1
// baseline (334.322 us; speedup 1.0000x reference)
//
#include <hip/hip_runtime.h>

#define B 16384
#define D 1024
#define CL_ALPHA 0.5f

// Pass 1: bincount(y_true)
__global__ void count_kernel(const int* __restrict__ y_true, int* __restrict__ counts) {
    int i = blockIdx.x * blockDim.x + threadIdx.x;
    if (i < B) atomicAdd(&counts[y_true[i]], 1);
}

// Pass 2: fused gather + diff^2 + reduction.
// One block per sample row i. Each of 256 threads handles one float4 (4 elems)
// of the 1024-wide row.
__global__ __launch_bounds__(256) void loss_kernel(const int* __restrict__ y_true,
                                                   const float* __restrict__ y_pred,
                                                   const float* __restrict__ centers,
                                                   const int* __restrict__ counts,
                                                   float* __restrict__ out) {
    const int i = blockIdx.x;
    const int j = y_true[i];       // gathered class for sample i
    const int k = y_true[j];       // class used to update center row j
    const float c = (float)counts[k];
    const float inv = CL_ALPHA / (c + 1.0f);

    const int t = threadIdx.x;
    const float4* yp_i = (const float4*)(y_pred + (size_t)i * D);
    const float4* ce_j = (const float4*)(centers + (size_t)j * D);
    const float4* ce_k = (const float4*)(centers + (size_t)k * D);
    const float4* yp_j = (const float4*)(y_pred + (size_t)j * D);

    float4 a  = yp_i[t];
    float4 bj = ce_j[t];
    float4 ck = ce_k[t];
    float4 yj = yp_j[t];

    float dx = a.x - bj.x + inv * (ck.x - yj.x);
    float dy = a.y - bj.y + inv * (ck.y - yj.y);
    float dz = a.z - bj.z + inv * (ck.z - yj.z);
    float dw = a.w - bj.w + inv * (ck.w - yj.w);
    float acc = dx * dx + dy * dy + dz * dz + dw * dw;

    // wave-64 shuffle reduction
    #pragma unroll
    for (int off = 32; off > 0; off >>= 1)
        acc += __shfl_down(acc, off, 64);

    __shared__ float smem[4];
    const int lane = t & 63;
    const int wave = t >> 6;
    if (lane == 0) smem[wave] = acc;
    __syncthreads();
    if (t == 0) {
        float s = smem[0] + smem[1] + smem[2] + smem[3];
        atomicAdd(out, s * (1.0f / ((float)B * (float)D)));
    }
}

extern "C" void kernel_launch(void* const* d_in, const int* in_sizes, int n_in,
                              void* d_out, int out_size, void* d_ws, size_t ws_size,
                              hipStream_t stream) {
    const int*   y_true  = (const int*)d_in[0];
    const float* y_pred  = (const float*)d_in[1];
    const float* centers = (const float*)d_in[2];
    float* out = (float*)d_out;
    int* counts = (int*)d_ws;   // 16384 * 4 B = 64 KB scratch

    hipMemsetAsync(counts, 0, B * sizeof(int), stream);
    hipMemsetAsync(out, 0, sizeof(float), stream);

    count_kernel<<<B / 256, 256, 0, stream>>>(y_true, counts);
    loss_kernel<<<B, 256, 0, stream>>>(y_true, y_pred, centers, counts, out);
}

// Round 2
// 161.715 us; speedup vs baseline: 2.0674x; 2.0674x over previous
//
#include <hip/hip_runtime.h>

#define B 16384
#define D 1024
#define CL_ALPHA 0.5f

// Pass 1: bincount(y_true)
__global__ void count_kernel(const int* __restrict__ y_true, int* __restrict__ counts) {
    int i = blockIdx.x * blockDim.x + threadIdx.x;
    if (i < B) atomicAdd(&counts[y_true[i]], 1);
}

// Pass 1.5: precompute k = y_true[y_true[i]] and inv = alpha/(counts[k]+1).
// 16384 independent threads fully overlap the 3-deep dependent-load chain.
__global__ void prep_kernel(const int* __restrict__ y_true,
                            const int* __restrict__ counts,
                            int* __restrict__ k_arr,
                            float* __restrict__ inv_arr) {
    int i = blockIdx.x * blockDim.x + threadIdx.x;
    if (i >= B) return;
    int j = y_true[i];
    int k = y_true[j];
    k_arr[i] = k;
    inv_arr[i] = CL_ALPHA / ((float)counts[k] + 1.0f);
}

// Pass 2: fused gather + diff^2 + block reduction -> partials[i]. No atomics.
__global__ __launch_bounds__(256) void loss_kernel(const int* __restrict__ y_true,
                                                   const float* __restrict__ y_pred,
                                                   const float* __restrict__ centers,
                                                   const int* __restrict__ k_arr,
                                                   const float* __restrict__ inv_arr,
                                                   float* __restrict__ partials) {
    const int i = blockIdx.x;
    // Three independent single-latency loads (no chain):
    const int j = y_true[i];
    const int k = k_arr[i];
    const float inv = inv_arr[i];

    const int t = threadIdx.x;
    const float4* yp_i = (const float4*)(y_pred + (size_t)i * D);
    const float4* ce_j = (const float4*)(centers + (size_t)j * D);
    const float4* ce_k = (const float4*)(centers + (size_t)k * D);
    const float4* yp_j = (const float4*)(y_pred + (size_t)j * D);

    float4 a  = yp_i[t];
    float4 bj = ce_j[t];
    float4 ck = ce_k[t];
    float4 yj = yp_j[t];

    float dx = a.x - bj.x + inv * (ck.x - yj.x);
    float dy = a.y - bj.y + inv * (ck.y - yj.y);
    float dz = a.z - bj.z + inv * (ck.z - yj.z);
    float dw = a.w - bj.w + inv * (ck.w - yj.w);
    float acc = dx * dx + dy * dy + dz * dz + dw * dw;

    #pragma unroll
    for (int off = 32; off > 0; off >>= 1)
        acc += __shfl_down(acc, off, 64);

    __shared__ float smem[4];
    const int lane = t & 63;
    const int wave = t >> 6;
    if (lane == 0) smem[wave] = acc;
    __syncthreads();
    if (t == 0)
        partials[i] = smem[0] + smem[1] + smem[2] + smem[3];
}

// Pass 3: reduce 16384 partials -> out[0]. One block, 1024 threads.
__global__ __launch_bounds__(1024) void finalize_kernel(const float* __restrict__ partials,
                                                        float* __restrict__ out) {
    const int t = threadIdx.x;
    const float4* p4 = (const float4*)partials;  // 4096 float4s
    float acc = 0.0f;
    #pragma unroll
    for (int w = 0; w < 4; ++w) {
        float4 v = p4[t + 1024 * w];
        acc += v.x + v.y + v.z + v.w;
    }
    #pragma unroll
    for (int off = 32; off > 0; off >>= 1)
        acc += __shfl_down(acc, off, 64);

    __shared__ float smem[16];
    const int lane = t & 63;
    const int wave = t >> 6;
    if (lane == 0) smem[wave] = acc;
    __syncthreads();
    if (t == 0) {
        float s = 0.0f;
        #pragma unroll
        for (int w = 0; w < 16; ++w) s += smem[w];
        out[0] = s * (1.0f / ((float)B * (float)D));
    }
}

extern "C" void kernel_launch(void* const* d_in, const int* in_sizes, int n_in,
                              void* d_out, int out_size, void* d_ws, size_t ws_size,
                              hipStream_t stream) {
    const int*   y_true  = (const int*)d_in[0];
    const float* y_pred  = (const float*)d_in[1];
    const float* centers = (const float*)d_in[2];
    float* out = (float*)d_out;

    // Workspace layout: counts | k_arr | inv_arr | partials  (64 KB each)
    int*   counts   = (int*)d_ws;
    int*   k_arr    = counts + B;
    float* inv_arr  = (float*)(k_arr + B);
    float* partials = inv_arr + B;

    hipMemsetAsync(counts, 0, B * sizeof(int), stream);

    count_kernel<<<B / 256, 256, 0, stream>>>(y_true, counts);
    prep_kernel<<<B / 256, 256, 0, stream>>>(y_true, counts, k_arr, inv_arr);
    loss_kernel<<<B, 256, 0, stream>>>(y_true, y_pred, centers, k_arr, inv_arr, partials);
    finalize_kernel<<<1, 1024, 0, stream>>>(partials, out);
}

// Round 3
// 160.886 us; speedup vs baseline: 2.0780x; 1.0052x over previous
//
#include <hip/hip_runtime.h>

#define B 16384
#define D 1024
#define CL_ALPHA 0.5f
#define ROWS 8                 // samples per block
#define NBLK (B / ROWS)        // 2048 blocks

// Pass 1: bincount(y_true)
__global__ void count_kernel(const int* __restrict__ y_true, int* __restrict__ counts) {
    int i = blockIdx.x * blockDim.x + threadIdx.x;
    if (i < B) atomicAdd(&counts[y_true[i]], 1);
}

// Pass 1.5: precompute k = y_true[y_true[i]] and inv = alpha/(counts[k]+1).
__global__ void prep_kernel(const int* __restrict__ y_true,
                            const int* __restrict__ counts,
                            int* __restrict__ k_arr,
                            float* __restrict__ inv_arr) {
    int i = blockIdx.x * blockDim.x + threadIdx.x;
    if (i >= B) return;
    int j = y_true[i];
    int k = y_true[j];
    k_arr[i] = k;
    inv_arr[i] = CL_ALPHA / ((float)counts[k] + 1.0f);
}

// Pass 2: 8 samples per block. 256 threads; thread t covers float4 lane t of
// each 1024-wide row. Single reduction + store per block.
__global__ __launch_bounds__(256) void loss_kernel(const int* __restrict__ y_true,
                                                   const float* __restrict__ y_pred,
                                                   const float* __restrict__ centers,
                                                   const int* __restrict__ k_arr,
                                                   const float* __restrict__ inv_arr,
                                                   float* __restrict__ partials) {
    const int base = blockIdx.x * ROWS;
    const int t = threadIdx.x;

    // Uniform per-block metadata (scalarizable loads)
    int   js[ROWS], ks[ROWS];
    float invs[ROWS];
    #pragma unroll
    for (int r = 0; r < ROWS; ++r) {
        js[r]   = y_true[base + r];
        ks[r]   = k_arr[base + r];
        invs[r] = inv_arr[base + r];
    }

    float acc = 0.0f;
    #pragma unroll
    for (int r = 0; r < ROWS; ++r) {
        const int i = base + r;
        const int j = js[r];
        const int k = ks[r];
        const float inv = invs[r];

        float4 a  = ((const float4*)(y_pred  + (size_t)i * D))[t];
        float4 bj = ((const float4*)(centers + (size_t)j * D))[t];
        float4 ck = ((const float4*)(centers + (size_t)k * D))[t];
        float4 yj = ((const float4*)(y_pred  + (size_t)j * D))[t];

        float dx = a.x - bj.x + inv * (ck.x - yj.x);
        float dy = a.y - bj.y + inv * (ck.y - yj.y);
        float dz = a.z - bj.z + inv * (ck.z - yj.z);
        float dw = a.w - bj.w + inv * (ck.w - yj.w);
        acc += dx * dx + dy * dy + dz * dz + dw * dw;
    }

    #pragma unroll
    for (int off = 32; off > 0; off >>= 1)
        acc += __shfl_down(acc, off, 64);

    __shared__ float smem[4];
    const int lane = t & 63;
    const int wave = t >> 6;
    if (lane == 0) smem[wave] = acc;
    __syncthreads();
    if (t == 0)
        partials[blockIdx.x] = smem[0] + smem[1] + smem[2] + smem[3];
}

// Pass 3: reduce 2048 partials -> out[0]. One block, 1024 threads.
__global__ __launch_bounds__(1024) void finalize_kernel(const float* __restrict__ partials,
                                                        float* __restrict__ out) {
    const int t = threadIdx.x;
    float acc = partials[t] + partials[t + 1024];

    #pragma unroll
    for (int off = 32; off > 0; off >>= 1)
        acc += __shfl_down(acc, off, 64);

    __shared__ float smem[16];
    const int lane = t & 63;
    const int wave = t >> 6;
    if (lane == 0) smem[wave] = acc;
    __syncthreads();
    if (t == 0) {
        float s = 0.0f;
        #pragma unroll
        for (int w = 0; w < 16; ++w) s += smem[w];
        out[0] = s * (1.0f / ((float)B * (float)D));
    }
}

extern "C" void kernel_launch(void* const* d_in, const int* in_sizes, int n_in,
                              void* d_out, int out_size, void* d_ws, size_t ws_size,
                              hipStream_t stream) {
    const int*   y_true  = (const int*)d_in[0];
    const float* y_pred  = (const float*)d_in[1];
    const float* centers = (const float*)d_in[2];
    float* out = (float*)d_out;

    // Workspace layout: counts | k_arr | inv_arr | partials
    int*   counts   = (int*)d_ws;
    int*   k_arr    = counts + B;
    float* inv_arr  = (float*)(k_arr + B);
    float* partials = inv_arr + B;

    hipMemsetAsync(counts, 0, B * sizeof(int), stream);

    count_kernel<<<256, 64, 0, stream>>>(y_true, counts);
    prep_kernel<<<256, 64, 0, stream>>>(y_true, counts, k_arr, inv_arr);
    loss_kernel<<<NBLK, 256, 0, stream>>>(y_true, y_pred, centers, k_arr, inv_arr, partials);
    finalize_kernel<<<1, 1024, 0, stream>>>(partials, out);
}